// Round 1
// baseline (134.368 us; speedup 1.0000x reference)
//
#include <hip/hip_runtime.h>

#define KS   21
#define PAD  10
#define HH   48
#define WW   48
#define CC   3
#define NB   4
#define NPIX (HH*WW*CC)   /* 6912 */
#define NTOT (NB*NPIX)    /* 27648 */
#define QSPLIT 8
#define QCH  (NPIX/QSPLIT) /* 864 */

__device__ __forceinline__ float fast_exp2(float x) {
#if __has_builtin(__builtin_amdgcn_exp2f)
    return __builtin_amdgcn_exp2f(x);
#else
    return __expf(x * 0.6931471805599453f);
#endif
}
__device__ __forceinline__ float fast_rcp(float x) {
#if __has_builtin(__builtin_amdgcn_rcpf)
    return __builtin_amdgcn_rcpf(x);
#else
    return 1.0f / x;
#endif
}

// taps layout: taps[set*63 + f*21 + i], set: 0=m, 1=w, 2=g
// 1D L2-normalized Gaussian; outer product == reference's 2D L2-normalized kernel
// (amp cancels; 2D sum-of-squares factorizes into (1D sum-of-squares)^2).
__global__ void taps_kernel(const float* __restrict__ gm, const float* __restrict__ gw,
                            const float* __restrict__ gg, float* __restrict__ taps) {
    int t = threadIdx.x;
    if (t >= 9 * KS) return;
    int set = t / (3 * KS);
    int f   = (t / KS) % 3;
    int i   = t % KS;
    const float* g = (set == 0) ? gm : (set == 1) ? gw : gg;
    float sigma  = 1.0f / g[f];
    float inv2s2 = 0.5f / (sigma * sigma);
    const float step = 21.0f / 640.0f;   // linspace(0, 21/32, 21) spacing
    const float mean = 21.0f / 64.0f;
    float r = (float)i * step - mean;
    float v = expf(-r * r * inv2s2);
    float ss = 0.0f;
    for (int j = 0; j < KS; ++j) {
        float rj = (float)j * step - mean;
        float vj = expf(-rj * rj * inv2s2);
        ss += vj * vj;
    }
    taps[t] = v * rsqrtf(ss);
}

// Horizontal 1D conv, two tap sets sharing loads. idx -> (n,h,w,f), NHWC.
__global__ void conv_h2(const float* __restrict__ in,
                        const float* __restrict__ tapsA, const float* __restrict__ tapsB,
                        float* __restrict__ outA, float* __restrict__ outB) {
    int idx = blockIdx.x * blockDim.x + threadIdx.x;
    if (idx >= NTOT) return;
    int f   = idx % CC;
    int w   = (idx / CC) % WW;
    int row = idx / (CC * WW);          // n*H + h
    const float* ta = tapsA + f * KS;
    const float* tb = tapsB + f * KS;
    const float* base = in + row * (WW * CC) + f;
    float a = 0.f, b = 0.f;
#pragma unroll
    for (int k = 0; k < KS; ++k) {
        int ww = w + k - PAD;
        if (ww >= 0 && ww < WW) {
            float v = base[ww * CC];
            a += v * ta[k];
            b += v * tb[k];
        }
    }
    outA[idx] = a;
    outB[idx] = b;
}

// Vertical 1D conv, two inputs/outputs (A: taps_m, B: taps_g).
__global__ void conv_v2(const float* __restrict__ inA, const float* __restrict__ inB,
                        const float* __restrict__ tapsA, const float* __restrict__ tapsB,
                        float* __restrict__ outA, float* __restrict__ outB) {
    int idx = blockIdx.x * blockDim.x + threadIdx.x;
    if (idx >= NTOT) return;
    int f = idx % CC;
    int w = (idx / CC) % WW;
    int h = (idx / (CC * WW)) % HH;
    int n = idx / (CC * WW * HH);
    const float* ta = tapsA + f * KS;
    const float* tb = tapsB + f * KS;
    float a = 0.f, b = 0.f;
#pragma unroll
    for (int k = 0; k < KS; ++k) {
        int hh = h + k - PAD;
        if (hh >= 0 && hh < HH) {
            int off = ((n * HH + hh) * WW + w) * CC + f;
            a += inA[off] * ta[k];
            b += inB[off] * tb[k];
        }
    }
    outA[idx] = a;
    outB[idx] = b;
}

// diffsum[n][p] += sum over q-chunk of tanh(x_p - b_q)
// tanh(z) = 1 - 2/(exp(2z)+1); exp2 arg = c*x - c*b with c = 2*log2(e) -> 1 FMA.
__global__ void diff_kernel(const float* __restrict__ inputs, const float* __restrict__ blur,
                            float* __restrict__ diffsum) {
    __shared__ float sb[QCH];
    int n  = blockIdx.y;
    int p  = blockIdx.x * 256 + threadIdx.x;
    int q0 = blockIdx.z * QCH;
    const float* b = blur + n * NPIX + q0;
    for (int i = threadIdx.x; i < QCH; i += 256) sb[i] = b[i];
    __syncthreads();
    float x  = inputs[n * NPIX + p];
    const float c = 2.8853900817779268f;   // 2*log2(e)
    float cx = c * x;
    float acc = 0.0f;                      // sum of 1/(e^{2z}+1)
#pragma unroll 8
    for (int q = 0; q < QCH; ++q) {
        float e = fast_exp2(fmaf(-c, sb[q], cx));
        acc += fast_rcp(e + 1.0f);
    }
    float s = (float)QCH - 2.0f * acc;     // sum of tanh over chunk
    atomicAdd(&diffsum[n * NPIX + p], s);
}

// Horizontal conv of diffsum with taps_w, folding the 1/NPIX mean.
__global__ void conv_h1(const float* __restrict__ in, const float* __restrict__ taps,
                        float* __restrict__ out) {
    int idx = blockIdx.x * blockDim.x + threadIdx.x;
    if (idx >= NTOT) return;
    int f   = idx % CC;
    int w   = (idx / CC) % WW;
    int row = idx / (CC * WW);
    const float* ta = taps + f * KS;
    const float* base = in + row * (WW * CC) + f;
    float a = 0.f;
#pragma unroll
    for (int k = 0; k < KS; ++k) {
        int ww = w + k - PAD;
        if (ww >= 0 && ww < WW) a += base[ww * CC] * ta[k];
    }
    out[idx] = a * (1.0f / (float)NPIX);
}

// Vertical conv of tmp_w with taps_w; out = first_term - second_term.
__global__ void conv_v1_final(const float* __restrict__ in, const float* __restrict__ taps,
                              const float* __restrict__ first, float* __restrict__ out) {
    int idx = blockIdx.x * blockDim.x + threadIdx.x;
    if (idx >= NTOT) return;
    int f = idx % CC;
    int w = (idx / CC) % WW;
    int h = (idx / (CC * WW)) % HH;
    int n = idx / (CC * WW * HH);
    const float* ta = taps + f * KS;
    float a = 0.f;
#pragma unroll
    for (int k = 0; k < KS; ++k) {
        int hh = h + k - PAD;
        if (hh >= 0 && hh < HH) a += in[((n * HH + hh) * WW + w) * CC + f] * ta[k];
    }
    out[idx] = first[idx] - a;
}

extern "C" void kernel_launch(void* const* d_in, const int* in_sizes, int n_in,
                              void* d_out, int out_size, void* d_ws, size_t ws_size,
                              hipStream_t stream) {
    const float* in  = (const float*)d_in[0];
    const float* gm  = (const float*)d_in[1];
    const float* gw  = (const float*)d_in[2];
    const float* gg  = (const float*)d_in[3];
    float* out = (float*)d_out;

    float* wsf    = (float*)d_ws;
    float* taps   = wsf;               // 189 floats (padded to 256)
    float* taps_m = taps;
    float* taps_w = taps + 63;
    float* taps_g = taps + 126;
    float* buf1   = wsf + 256;         // tmp_m, later diffsum
    float* buf2   = buf1 + NTOT;       // tmp_g, later tmp_w
    float* buf3   = buf2 + NTOT;       // first_term
    float* buf4   = buf3 + NTOT;       // blurred

    const int blocks = (NTOT + 255) / 256;

    taps_kernel<<<1, 256, 0, stream>>>(gm, gw, gg, taps);
    conv_h2<<<blocks, 256, 0, stream>>>(in, taps_m, taps_g, buf1, buf2);
    conv_v2<<<blocks, 256, 0, stream>>>(buf1, buf2, taps_m, taps_g, buf3, buf4);
    hipMemsetAsync(buf1, 0, NTOT * sizeof(float), stream);
    diff_kernel<<<dim3(NPIX / 256, NB, QSPLIT), 256, 0, stream>>>(in, buf4, buf1);
    conv_h1<<<blocks, 256, 0, stream>>>(buf1, taps_w, buf2);
    conv_v1_final<<<blocks, 256, 0, stream>>>(buf2, taps_w, buf3, out);
}

// Round 2
// 102.912 us; speedup vs baseline: 1.3057x; 1.3057x over previous
//
#include <hip/hip_runtime.h>

#define KS   21
#define PAD  10
#define HH   48
#define WW   48
#define CC   3
#define NB   4
#define NPIX (HH*WW*CC)   /* 6912 */
#define NTOT (NB*NPIX)    /* 27648 */
#define QS   8
#define TPB1 1024
#define CTAN 2.8853900817779268f   /* 2*log2(e) */
#define SATMARGIN 4.0f             /* |z|>=4 -> tanh within 6.7e-4 of +/-1 */

__device__ __forceinline__ float fast_exp2(float x) {
#if __has_builtin(__builtin_amdgcn_exp2f)
    return __builtin_amdgcn_exp2f(x);
#else
    return __expf(x * 0.6931471805599453f);
#endif
}
__device__ __forceinline__ float fast_rcp(float x) {
#if __has_builtin(__builtin_amdgcn_rcpf)
    return __builtin_amdgcn_rcpf(x);
#else
    return 1.0f / x;
#endif
}

// Kernel 1: one block per image (1024 thr).
// Phases: taps (m,w,g; 1D L2-normalized == separable factorization of the
// reference's 2D L2-normalized kernel) -> load image to LDS + x min/max
// reduction -> h-conv (m,g) in LDS -> v-conv: first_term to global, blurred
// classified: |x-b| guaranteed >= SATMARGIN -> tanh = +/-1 (counted), else
// append c*b to compacted active list (wave-aggregated LDS atomics).
// diffsum pre-filled with the net saturated contribution.
__global__ __launch_bounds__(TPB1) void setup_kernel(
    const float* __restrict__ in, const float* __restrict__ gm,
    const float* __restrict__ gw, const float* __restrict__ gg,
    float* __restrict__ taps_w_g, float* __restrict__ first,
    float* __restrict__ active, int* __restrict__ meta,
    float* __restrict__ diffsum)
{
    __shared__ float simg[NPIX];
    __shared__ float hA[NPIX];
    __shared__ float hB[NPIX];
    __shared__ float taps[192];
    __shared__ float redmax[16], redmin[16];
    __shared__ float sxmax, sxmin;
    __shared__ int s_cnt, s_net;

    const int t = threadIdx.x;
    const int n = blockIdx.x;
    if (t == 0) { s_cnt = 0; s_net = 0; }

    if (t < 189) {                      // taps: m[0,63) w[63,126) g[126,189)
        int set = t / 63, f = (t / 21) % 3, i = t % 21;
        const float* g = set == 0 ? gm : (set == 1 ? gw : gg);
        float sigma  = 1.0f / g[f];
        float inv2s2 = 0.5f / (sigma * sigma);
        const float step = 21.0f / 640.0f, mean = 21.0f / 64.0f;
        float r = (float)i * step - mean;
        float v = expf(-r * r * inv2s2);
        float ss = 0.0f;
        for (int j = 0; j < 21; ++j) {
            float rj = (float)j * step - mean;
            float vj = expf(-rj * rj * inv2s2);
            ss += vj * vj;
        }
        float val = v * rsqrtf(ss);
        taps[t] = val;
        if (set == 1) taps_w_g[t - 63] = val;   // all 4 blocks write same values
    }

    float pmax = -3.4e38f, pmin = 3.4e38f;
    for (int i = t; i < NPIX; i += TPB1) {
        float v = in[n * NPIX + i];
        simg[i] = v;
        pmax = fmaxf(pmax, v); pmin = fminf(pmin, v);
    }
    for (int off = 32; off; off >>= 1) {
        pmax = fmaxf(pmax, __shfl_down(pmax, off));
        pmin = fminf(pmin, __shfl_down(pmin, off));
    }
    if ((t & 63) == 0) { redmax[t >> 6] = pmax; redmin[t >> 6] = pmin; }
    __syncthreads();
    if (t == 0) {
        float mx = redmax[0], mn = redmin[0];
        for (int i = 1; i < 16; ++i) { mx = fmaxf(mx, redmax[i]); mn = fminf(mn, redmin[i]); }
        sxmax = mx; sxmin = mn;
    }
    __syncthreads();

    for (int i = t; i < NPIX; i += TPB1) {       // h-conv (m,g)
        int f = i % 3, w = (i / 3) % 48;
        const float* tm = &taps[f * 21];
        const float* tg = &taps[126 + f * 21];
        float a = 0.f, b = 0.f;
        int klo = max(0, 10 - w), khi = min(21, 58 - w);
        for (int k = klo; k < khi; ++k) {
            float v = simg[i + (k - 10) * 3];
            a += v * tm[k]; b += v * tg[k];
        }
        hA[i] = a; hB[i] = b;
    }
    __syncthreads();

    const int lane = t & 63;
    const unsigned long long ltmask = (1ull << lane) - 1ull;
    const float xmax = sxmax, xmin = sxmin;
    for (int i = t; i < NPIX; i += TPB1) {       // v-conv + classify/compact
        int f = i % 3, h = i / 144;
        const float* tm = &taps[f * 21];
        const float* tg = &taps[126 + f * 21];
        float a = 0.f, b = 0.f;
        int klo = max(0, 10 - h), khi = min(21, 58 - h);
        for (int k = klo; k < khi; ++k) {
            int off = i + (k - 10) * 144;
            a += hA[off] * tm[k]; b += hB[off] * tg[k];
        }
        first[n * NPIX + i] = a;
        bool satneg = (b >= xmax + SATMARGIN);   // tanh(x-b) == -1 for all x
        bool satpos = (b <= xmin - SATMARGIN);   // tanh(x-b) == +1 for all x
        bool act = !(satneg || satpos);
        unsigned long long mball = __ballot(act);
        int nact = __popcll(mball);
        int base = 0;
        if (lane == 0 && nact) base = atomicAdd(&s_cnt, nact);
        base = __shfl(base, 0);
        if (act) active[n * NPIX + base + __popcll(mball & ltmask)] = CTAN * b;
        int netc = __popcll(__ballot(satpos)) - __popcll(__ballot(satneg));
        if (lane == 0 && netc) atomicAdd(&s_net, netc);
    }
    __syncthreads();
    if (t == 0) { meta[2 * n] = s_cnt; meta[2 * n + 1] = s_net; }
    float netf = (float)s_net;
    for (int i = t; i < NPIX; i += TPB1) diffsum[n * NPIX + i] = netf;
}

// Kernel 2: diffsum[n][p] += sum over active-chunk of tanh(x_p - b_q).
// tanh(z) = 1 - 2/(e^{2z}+1); exp2 arg = c*x - c*b, c*b staged in LDS.
__global__ __launch_bounds__(256) void diff_kernel(
    const float* __restrict__ in, const float* __restrict__ active,
    const int* __restrict__ meta, float* __restrict__ diffsum)
{
    __shared__ float sb[(NPIX + QS - 1) / QS];   // 864 worst case
    const int n = blockIdx.y, z = blockIdx.z;
    const int p = blockIdx.x * 256 + threadIdx.x;
    const int na = meta[2 * n];
    const int chunk = (na + QS - 1) / QS;
    const int q0 = z * chunk;
    int q1 = q0 + chunk; if (q1 > na) q1 = na;
    int len = q1 - q0; if (len < 0) len = 0;
    for (int i = threadIdx.x; i < len; i += 256) sb[i] = active[n * NPIX + q0 + i];
    __syncthreads();
    float cx = CTAN * in[n * NPIX + p];
    float acc = 0.0f;
#pragma unroll 4
    for (int q = 0; q < len; ++q) {
        float e = fast_exp2(cx - sb[q]);
        acc += fast_rcp(e + 1.0f);
    }
    float s = (float)len - 2.0f * acc;
    atomicAdd(&diffsum[n * NPIX + p], s);
}

// Kernel 3: one block per image. mean-scale -> separable w-conv in LDS ->
// out = first_term - second_term.
__global__ __launch_bounds__(TPB1) void final_kernel(
    const float* __restrict__ diffsum, const float* __restrict__ taps_w_g,
    const float* __restrict__ first, float* __restrict__ out)
{
    __shared__ float d[NPIX];
    __shared__ float t1[NPIX];
    __shared__ float tw[64];
    const int t = threadIdx.x, n = blockIdx.x;
    if (t < 63) tw[t] = taps_w_g[t];
    for (int i = t; i < NPIX; i += TPB1) d[i] = diffsum[n * NPIX + i] * (1.0f / (float)NPIX);
    __syncthreads();
    for (int i = t; i < NPIX; i += TPB1) {
        int f = i % 3, w = (i / 3) % 48;
        const float* ta = &tw[f * 21];
        float a = 0.f;
        int klo = max(0, 10 - w), khi = min(21, 58 - w);
        for (int k = klo; k < khi; ++k) a += d[i + (k - 10) * 3] * ta[k];
        t1[i] = a;
    }
    __syncthreads();
    for (int i = t; i < NPIX; i += TPB1) {
        int f = i % 3, h = i / 144;
        const float* ta = &tw[f * 21];
        float a = 0.f;
        int klo = max(0, 10 - h), khi = min(21, 58 - h);
        for (int k = klo; k < khi; ++k) a += t1[i + (k - 10) * 144] * ta[k];
        out[n * NPIX + i] = first[n * NPIX + i] - a;
    }
}

extern "C" void kernel_launch(void* const* d_in, const int* in_sizes, int n_in,
                              void* d_out, int out_size, void* d_ws, size_t ws_size,
                              hipStream_t stream) {
    const float* in = (const float*)d_in[0];
    const float* gm = (const float*)d_in[1];
    const float* gw = (const float*)d_in[2];
    const float* gg = (const float*)d_in[3];
    float* out = (float*)d_out;

    float* wsf       = (float*)d_ws;
    float* taps_w_g  = wsf;                  // 64
    int*   meta      = (int*)(wsf + 64);     // 8
    float* first     = wsf + 80;             // NTOT
    float* active    = first + NTOT;         // NTOT (worst case)
    float* diffsum   = active + NTOT;        // NTOT   -> total ~332 KB

    setup_kernel<<<NB, TPB1, 0, stream>>>(in, gm, gw, gg, taps_w_g, first, active, meta, diffsum);
    diff_kernel<<<dim3(NPIX / 256, NB, QS), 256, 0, stream>>>(in, active, meta, diffsum);
    final_kernel<<<NB, TPB1, 0, stream>>>(diffsum, taps_w_g, first, out);
}